// Round 10
// baseline (2059.652 us; speedup 1.0000x reference)
//
#include <hip/hip_runtime.h>
#include <hip/hip_bf16.h>

typedef unsigned short u16;
typedef unsigned int u32;

#define Bb 16
#define Tt 1024
#define Dd 1024
#define Nn 64
#define Hh 16
#define Mm (Bb*Tt)

#define TILE_M 64
#define TILE_N 64
#define TILE_K 16

typedef float f32x4 __attribute__((ext_vector_type(4)));
typedef short s16x8 __attribute__((ext_vector_type(8)));

struct __align__(8) u16x4s { u16 x, y, z, w; };
struct slice16 { s16x8 lo, hi; };

__device__ __forceinline__ float bf2f(u16 u) { return __uint_as_float(((u32)u) << 16); }
__device__ __forceinline__ u16 f2bf(float f) {
    __hip_bfloat16 h = __float2bfloat16(f);
    return *reinterpret_cast<u16*>(&h);
}
__device__ __forceinline__ float sigf(float x) { return 1.0f / (1.0f + expf(-x)); }

__device__ __forceinline__ slice16 ldslice(const u16* p) {
    slice16 s;
    s.lo = *(const s16x8*)p;
    s.hi = *(const s16x8*)(p + 8);
    return s;
}

// ---------------- mix6 ----------------
__global__ __launch_bounds__(256)
void mix6_kernel(const float* __restrict__ x,
                 const float* __restrict__ cr, const float* __restrict__ ck,
                 const float* __restrict__ cv, const float* __restrict__ cw,
                 const float* __restrict__ ca, const float* __restrict__ cg,
                 u16* __restrict__ o0, u16* __restrict__ o1, u16* __restrict__ o2,
                 u16* __restrict__ o3, u16* __restrict__ o4, u16* __restrict__ o5)
{
    const int m = blockIdx.x;
    const int c0 = threadIdx.x * 4;
    const size_t base = (size_t)m * Dd + c0;
    float4 xc = *(const float4*)(x + base);
    float4 xp = make_float4(0.f, 0.f, 0.f, 0.f);
    if (m & (Tt - 1)) xp = *(const float4*)(x + base - Dd);
    float dx[4] = {xp.x - xc.x, xp.y - xc.y, xp.z - xc.z, xp.w - xc.w};
    float xv[4] = {xc.x, xc.y, xc.z, xc.w};
    const float* cfs[6] = {cr, ck, cv, cw, ca, cg};
    u16* outs[6] = {o0, o1, o2, o3, o4, o5};
#pragma unroll
    for (int s = 0; s < 6; ++s) {
        float4 cf = *(const float4*)(cfs[s] + c0);
        float c4[4] = {cf.x, cf.y, cf.z, cf.w};
        u16x4s ov;
        u16* op = &ov.x;
#pragma unroll
        for (int l = 0; l < 4; ++l) op[l] = f2bf(fmaf(dx[l], c4[l], xv[l]));
        *(u16x4s*)(outs[s] + base) = ov;
    }
}

// ---------------- small fp32-compute GEMM for LoRA stage-1 ----------------
__global__ __launch_bounds__(256)
void sgemm_small(const u16* __restrict__ A, int lda,
                 const float* __restrict__ Bw, int ldb,
                 u16* __restrict__ C, int ldc,
                 int N, int K, int act)
{
    __shared__ float As[TILE_K][TILE_M + 1];
    __shared__ float Bs[TILE_K][TILE_N + 1];
    const int tid = threadIdx.x;
    const int tx = tid & 15, ty = tid >> 4;
    const int bm = blockIdx.x * TILE_M;
    const int bn = blockIdx.y * TILE_N;

    float acc[4][4] = {};

    for (int k0 = 0; k0 < K; k0 += TILE_K) {
#pragma unroll
        for (int l = 0; l < 4; ++l) {
            int idx = l * 256 + tid;
            int kk = idx & 15, mm = idx >> 4;
            As[kk][mm] = bf2f(A[(size_t)(bm + mm) * lda + k0 + kk]);
        }
#pragma unroll
        for (int l = 0; l < 4; ++l) {
            int idx = l * 256 + tid;
            int nn = idx & 63, kk = idx >> 6;
            int gn = bn + nn;
            Bs[kk][nn] = (gn < N) ? Bw[(size_t)(k0 + kk) * ldb + gn] : 0.0f;
        }
        __syncthreads();
#pragma unroll
        for (int kk = 0; kk < TILE_K; ++kk) {
            float af[4], bf[4];
#pragma unroll
            for (int i = 0; i < 4; ++i) af[i] = As[kk][ty * 4 + i];
#pragma unroll
            for (int j = 0; j < 4; ++j) bf[j] = Bs[kk][tx * 4 + j];
#pragma unroll
            for (int i = 0; i < 4; ++i)
#pragma unroll
                for (int j = 0; j < 4; ++j)
                    acc[i][j] = fmaf(af[i], bf[j], acc[i][j]);
        }
        __syncthreads();
    }

#pragma unroll
    for (int i = 0; i < 4; ++i) {
        int gm = bm + ty * 4 + i;
#pragma unroll
        for (int j = 0; j < 4; ++j) {
            int gn = bn + tx * 4 + j;
            if (gn >= N) continue;
            float v = acc[i][j];
            if (act == 1) v = tanhf(v);
            else if (act == 2) v = sigf(v);
            C[(size_t)gm * ldc + gn] = f2bf(v);
        }
    }
}

// ---------------- MFMA GEMM ----------------
template<int ACT, bool HAS_BIAS>
__global__ __launch_bounds__(256)
void gemm_mfma(const u16* __restrict__ A, int lda,
               const float* __restrict__ W,
               const float* __restrict__ bias,
               u16* __restrict__ C, int K)
{
    __shared__ u16 As[128][40];
    __shared__ u16 Bs[128][40];
    const int tid = threadIdx.x;
    const int bm = blockIdx.x * 128, bn = blockIdx.y * 128;
    const int lane = tid & 63, w = tid >> 6;
    const int wr = w >> 1, wc = w & 1;
    const int lr = lane & 15, kg = lane >> 4;

    f32x4 acc[4][4];
#pragma unroll
    for (int m = 0; m < 4; ++m)
#pragma unroll
        for (int n = 0; n < 4; ++n) acc[m][n] = (f32x4){0.f, 0.f, 0.f, 0.f};

    for (int k0 = 0; k0 < K; k0 += 32) {
        {
            int row = tid >> 2, part = tid & 3;
            *(s16x8*)&As[row][part * 8] =
                *(const s16x8*)(A + (size_t)(bm + row) * lda + k0 + part * 8);
            row += 64;
            *(s16x8*)&As[row][part * 8] =
                *(const s16x8*)(A + (size_t)(bm + row) * lda + k0 + part * 8);
        }
        {
            int n4 = (tid & 31) * 4;
            int kp = tid >> 5;
#pragma unroll
            for (int it = 0; it < 2; ++it) {
                int k = 2 * (kp + it * 8);
                const float* wp = W + (size_t)(k0 + k) * 1024 + bn + n4;
                float4 wa = *(const float4*)wp;
                float4 wb = *(const float4*)(wp + 1024);
                *(u32*)&Bs[n4 + 0][k] = (u32)f2bf(wa.x) | ((u32)f2bf(wb.x) << 16);
                *(u32*)&Bs[n4 + 1][k] = (u32)f2bf(wa.y) | ((u32)f2bf(wb.y) << 16);
                *(u32*)&Bs[n4 + 2][k] = (u32)f2bf(wa.z) | ((u32)f2bf(wb.z) << 16);
                *(u32*)&Bs[n4 + 3][k] = (u32)f2bf(wa.w) | ((u32)f2bf(wb.w) << 16);
            }
        }
        __syncthreads();
        s16x8 af[4], bfr[4];
#pragma unroll
        for (int m = 0; m < 4; ++m)
            af[m] = *(const s16x8*)&As[wr * 64 + m * 16 + lr][kg * 8];
#pragma unroll
        for (int n = 0; n < 4; ++n)
            bfr[n] = *(const s16x8*)&Bs[wc * 64 + n * 16 + lr][kg * 8];
#pragma unroll
        for (int m = 0; m < 4; ++m)
#pragma unroll
            for (int n = 0; n < 4; ++n)
                acc[m][n] = __builtin_amdgcn_mfma_f32_16x16x32_bf16(af[m], bfr[n], acc[m][n], 0, 0, 0);
        __syncthreads();
    }

#pragma unroll
    for (int n = 0; n < 4; ++n) {
        int col = bn + wc * 64 + n * 16 + lr;
        float bv = HAS_BIAS ? bias[col] : 0.0f;
#pragma unroll
        for (int m = 0; m < 4; ++m) {
            int row0 = bm + wr * 64 + m * 16 + kg * 4;
#pragma unroll
            for (int r = 0; r < 4; ++r) {
                float v = acc[m][n][r] + bv;
                if (ACT == 2) v = sigf(v);
                else if (ACT == 3) {
                    float ww = -log1pf(expf(-v)) - 0.5f;
                    v = expf(-expf(ww));
                }
                C[(size_t)(row0 + r) * 1024 + col] = f2bf(v);
            }
        }
    }
}

// ---------------- W_o MFMA GEMM with fused relu-colmax -> atomicMax ----------------
__global__ __launch_bounds__(256)
void gemm_wo_mfma(const u16* __restrict__ A,
                  const float* __restrict__ W,
                  float* __restrict__ Hbuf)
{
    __shared__ u16 As[128][40];
    __shared__ u16 Bs[128][40];
    const int tid = threadIdx.x;
    const int bm = blockIdx.x * 128, bn = blockIdx.y * 128;
    const int lane = tid & 63, w = tid >> 6;
    const int wr = w >> 1, wc = w & 1;
    const int lr = lane & 15, kg = lane >> 4;

    f32x4 acc[4][4];
#pragma unroll
    for (int m = 0; m < 4; ++m)
#pragma unroll
        for (int n = 0; n < 4; ++n) acc[m][n] = (f32x4){0.f, 0.f, 0.f, 0.f};

    for (int k0 = 0; k0 < 1024; k0 += 32) {
        {
            int row = tid >> 2, part = tid & 3;
            *(s16x8*)&As[row][part * 8] =
                *(const s16x8*)(A + (size_t)(bm + row) * 1024 + k0 + part * 8);
            row += 64;
            *(s16x8*)&As[row][part * 8] =
                *(const s16x8*)(A + (size_t)(bm + row) * 1024 + k0 + part * 8);
        }
        {
            int n4 = (tid & 31) * 4;
            int kp = tid >> 5;
#pragma unroll
            for (int it = 0; it < 2; ++it) {
                int k = 2 * (kp + it * 8);
                const float* wp = W + (size_t)(k0 + k) * 1024 + bn + n4;
                float4 wa = *(const float4*)wp;
                float4 wb = *(const float4*)(wp + 1024);
                *(u32*)&Bs[n4 + 0][k] = (u32)f2bf(wa.x) | ((u32)f2bf(wb.x) << 16);
                *(u32*)&Bs[n4 + 1][k] = (u32)f2bf(wa.y) | ((u32)f2bf(wb.y) << 16);
                *(u32*)&Bs[n4 + 2][k] = (u32)f2bf(wa.z) | ((u32)f2bf(wb.z) << 16);
                *(u32*)&Bs[n4 + 3][k] = (u32)f2bf(wa.w) | ((u32)f2bf(wb.w) << 16);
            }
        }
        __syncthreads();
        s16x8 af[4], bfr[4];
#pragma unroll
        for (int m = 0; m < 4; ++m)
            af[m] = *(const s16x8*)&As[wr * 64 + m * 16 + lr][kg * 8];
#pragma unroll
        for (int n = 0; n < 4; ++n)
            bfr[n] = *(const s16x8*)&Bs[wc * 64 + n * 16 + lr][kg * 8];
#pragma unroll
        for (int m = 0; m < 4; ++m)
#pragma unroll
            for (int n = 0; n < 4; ++n)
                acc[m][n] = __builtin_amdgcn_mfma_f32_16x16x32_bf16(af[m], bfr[n], acc[m][n], 0, 0, 0);
        __syncthreads();
    }

    const int b = bm >> 10;
#pragma unroll
    for (int n = 0; n < 4; ++n) {
        float mv = -1e30f;
#pragma unroll
        for (int m = 0; m < 4; ++m)
#pragma unroll
            for (int r = 0; r < 4; ++r) mv = fmaxf(mv, acc[m][n][r]);
        mv = fmaxf(mv, __shfl_xor(mv, 16));
        mv = fmaxf(mv, __shfl_xor(mv, 32));
        mv = fmaxf(mv, 0.0f);
        if (lane < 16) {
            int col = bn + wc * 64 + n * 16 + lr;
            atomicMax((u32*)&Hbuf[b * Dd + col], __float_as_uint(mv));
        }
    }
}

// ---------------- kk / k-mod / b ----------------
__global__ __launch_bounds__(256)
void ew_kv_kernel(u16* __restrict__ kbuf, u16* __restrict__ abuf,
                  u16* __restrict__ kkbuf,
                  const float* __restrict__ k_k, const float* __restrict__ k_a)
{
    const int m = blockIdx.x;
    const int tid = threadIdx.x;
    const int c0 = tid * 4;
    const size_t base = (size_t)m * Dd + c0;
    u16x4s kv4 = *(const u16x4s*)(kbuf + base);
    u16x4s av4 = *(const u16x4s*)(abuf + base);
    float4 kkc = *(const float4*)(k_k + c0);
    float4 kac = *(const float4*)(k_a + c0);

    float kin[4] = {bf2f(kv4.x), bf2f(kv4.y), bf2f(kv4.z), bf2f(kv4.w)};
    float ain[4] = {bf2f(av4.x), bf2f(av4.y), bf2f(av4.z), bf2f(av4.w)};
    float kkc4[4] = {kkc.x, kkc.y, kkc.z, kkc.w};
    float kac4[4] = {kac.x, kac.y, kac.z, kac.w};

    float kr[4];
#pragma unroll
    for (int l = 0; l < 4; ++l) kr[l] = kin[l] * kkc4[l];
    float ss = kr[0]*kr[0] + kr[1]*kr[1] + kr[2]*kr[2] + kr[3]*kr[3];
#pragma unroll
    for (int mask = 1; mask < 16; mask <<= 1) ss += __shfl_xor(ss, mask);
    float inv = 1.0f / fmaxf(sqrtf(ss), 1e-12f);

    u16x4s kkv, kmv, bvv;
    u16* kkp = &kkv.x; u16* kmp = &kmv.x; u16* bvp = &bvv.x;
#pragma unroll
    for (int l = 0; l < 4; ++l) {
        float kkf = kr[l] * inv;
        kkp[l] = f2bf(kkf);
        kmp[l] = f2bf(kin[l] * (1.0f + (ain[l] - 1.0f) * kac4[l]));
        bvp[l] = f2bf(kkf * ain[l]);
    }
    *(u16x4s*)(kkbuf + base) = kkv;
    *(u16x4s*)(kbuf  + base) = kmv;
    *(u16x4s*)(abuf  + base) = bvv;
}

// ---------------- RWKV7 scan: LDS-free, register-slice, depth-2 prefetch ----------------
// Lane (il,q) of wave w owns S[w*16+il][16q..16q+16). It loads its 16-element
// slices of r/decay/k/kk/b directly from global (L1-broadcast across the 16
// lanes sharing q) and v[i] as a scalar. No LDS, no barriers.
__global__ __launch_bounds__(256)
void scan_kernel(const u16* __restrict__ rb, const u16* __restrict__ db,
                 const u16* __restrict__ kb, const u16* __restrict__ vb,
                 const u16* __restrict__ kkb, const u16* __restrict__ bvb,
                 u16* __restrict__ ob)
{
    const int blk = blockIdx.x;
    const int batch = blk >> 4, head = blk & 15;
    const int tid = threadIdx.x;
    const int w = tid >> 6;
    const int lane = tid & 63;
    const int q = lane & 3, il = lane >> 2;
    const int i = w * 16 + il;
    const int j0 = q * 16;

    const size_t rowbase = (size_t)batch * Tt * Dd + head * Nn;

    float S[16];
#pragma unroll
    for (int jj = 0; jj < 16; ++jj) S[jj] = 0.0f;

    // t=0 (current) and t=1 (next) slices
    slice16 cr, cd, ck_, cc, cb;
    u16 cv;
    {
        size_t o = rowbase + j0;
        cr = ldslice(rb + o); cd = ldslice(db + o); ck_ = ldslice(kb + o);
        cc = ldslice(kkb + o); cb = ldslice(bvb + o);
        cv = vb[rowbase + i];
    }
    slice16 nr = cr, nd = cd, nk = ck_, nc = cc, nb = cb;
    u16 nv = cv;
    if (Tt > 1) {
        size_t o = rowbase + Dd + j0;
        nr = ldslice(rb + o); nd = ldslice(db + o); nk = ldslice(kb + o);
        nc = ldslice(kkb + o); nb = ldslice(bvb + o);
        nv = vb[rowbase + Dd + i];
    }

    for (int t = 0; t < Tt; ++t) {
        // issue t+2 loads (land during ~2 compute phases)
        slice16 mr = nr, md = nd, mk = nk, mc = nc, mb = nb;
        u16 mv = nv;
        if (t + 2 < Tt) {
            size_t o = rowbase + (size_t)(t + 2) * Dd;
            mr = ldslice(rb + o + j0); md = ldslice(db + o + j0);
            mk = ldslice(kb + o + j0); mc = ldslice(kkb + o + j0);
            mb = ldslice(bvb + o + j0);
            mv = vb[o + i];
        }

        float vi = bf2f(cv);

        float sa = 0.0f;
#pragma unroll
        for (int jj = 0; jj < 8; ++jj) sa = fmaf(S[jj], bf2f((u16)cc.lo[jj]), sa);
#pragma unroll
        for (int jj = 0; jj < 8; ++jj) sa = fmaf(S[8 + jj], bf2f((u16)cc.hi[jj]), sa);
        sa = -sa;
        sa += __shfl_xor(sa, 1);
        sa += __shfl_xor(sa, 2);

        float op = 0.0f;
#pragma unroll
        for (int jj = 0; jj < 8; ++jj) {
            float Sv = S[jj] * bf2f((u16)cd.lo[jj]);
            Sv = fmaf(sa, bf2f((u16)cb.lo[jj]), Sv);
            Sv = fmaf(vi, bf2f((u16)ck_.lo[jj]), Sv);
            S[jj] = Sv;
            op = fmaf(Sv, bf2f((u16)cr.lo[jj]), op);
        }
#pragma unroll
        for (int jj = 0; jj < 8; ++jj) {
            float Sv = S[8 + jj] * bf2f((u16)cd.hi[jj]);
            Sv = fmaf(sa, bf2f((u16)cb.hi[jj]), Sv);
            Sv = fmaf(vi, bf2f((u16)ck_.hi[jj]), Sv);
            S[8 + jj] = Sv;
            op = fmaf(Sv, bf2f((u16)cr.hi[jj]), op);
        }
        op += __shfl_xor(op, 1);
        op += __shfl_xor(op, 2);
        if (q == 0) ob[rowbase + (size_t)t * Dd + i] = f2bf(op);

        // rotate registers: c <- n <- m
        cr = nr; cd = nd; ck_ = nk; cc = nc; cb = nb; cv = nv;
        nr = mr; nd = md; nk = mk; nc = mc; nb = mb; nv = mv;
    }
}

// ---------------- GroupNorm + bonus + gate ----------------
__global__ __launch_bounds__(256)
void gn_kernel(const u16* __restrict__ ob, const u16* __restrict__ rb,
               const u16* __restrict__ kb, const u16* __restrict__ vb,
               const u16* __restrict__ gb,
               const float* __restrict__ gn_w, const float* __restrict__ gn_b,
               const float* __restrict__ r_k, u16* __restrict__ o2)
{
    const int m = blockIdx.x;
    const int tid = threadIdx.x;
    const int c0 = tid * 4;
    const int h = tid >> 4;
    const int jh = c0 & 63;
    const size_t base = (size_t)m * Dd + c0;

    u16x4s ov4 = *(const u16x4s*)(ob + base);
    u16x4s rv4 = *(const u16x4s*)(rb + base);
    u16x4s kv4 = *(const u16x4s*)(kb + base);
    u16x4s vv4 = *(const u16x4s*)(vb + base);
    u16x4s gv4 = *(const u16x4s*)(gb + base);
    float4 rkc = *(const float4*)(r_k + h * 64 + jh);

    float ovv[4] = {bf2f(ov4.x), bf2f(ov4.y), bf2f(ov4.z), bf2f(ov4.w)};
    float rv[4] = {bf2f(rv4.x), bf2f(rv4.y), bf2f(rv4.z), bf2f(rv4.w)};
    float kv[4] = {bf2f(kv4.x), bf2f(kv4.y), bf2f(kv4.z), bf2f(kv4.w)};
    float vv[4] = {bf2f(vv4.x), bf2f(vv4.y), bf2f(vv4.z), bf2f(vv4.w)};
    float gv[4] = {bf2f(gv4.x), bf2f(gv4.y), bf2f(gv4.z), bf2f(gv4.w)};
    float rk4[4] = {rkc.x, rkc.y, rkc.z, rkc.w};

    float s1 = ovv[0] + ovv[1] + ovv[2] + ovv[3];
    float s2 = ovv[0]*ovv[0] + ovv[1]*ovv[1] + ovv[2]*ovv[2] + ovv[3]*ovv[3];
    float sb = rv[0]*kv[0]*rk4[0] + rv[1]*kv[1]*rk4[1] + rv[2]*kv[2]*rk4[2] + rv[3]*kv[3]*rk4[3];
#pragma unroll
    for (int mask = 1; mask < 16; mask <<= 1) {
        s1 += __shfl_xor(s1, mask);
        s2 += __shfl_xor(s2, mask);
        sb += __shfl_xor(sb, mask);
    }
    float mu = s1 * (1.0f / 64.0f);
    float var = s2 * (1.0f / 64.0f) - mu * mu;
    float rstd = rsqrtf(var + 6.4e-4f);

    float4 gwv = *(const float4*)(gn_w + c0);
    float4 gbv = *(const float4*)(gn_b + c0);
    float gw4[4] = {gwv.x, gwv.y, gwv.z, gwv.w};
    float gb4[4] = {gbv.x, gbv.y, gbv.z, gbv.w};

    u16x4s outv; u16* op = &outv.x;
#pragma unroll
    for (int l = 0; l < 4; ++l) {
        float v = (((ovv[l] - mu) * rstd) * gw4[l] + gb4[l] + sb * vv[l]) * gv[l];
        op[l] = f2bf(v);
    }
    *(u16x4s*)(o2 + base) = outv;
}

__global__ __launch_bounds__(256)
void zero_kernel(float* __restrict__ p, int n)
{
    int i = blockIdx.x * 256 + threadIdx.x;
    if (i < n) p[i] = 0.0f;
}

__global__ __launch_bounds__(256)
void cls_kernel(const float* __restrict__ hp, const float* __restrict__ Wc,
                const float* __restrict__ bc, float* __restrict__ out)
{
    const int p = blockIdx.x;
    const int b = p >> 1, c = p & 1;
    const int tid = threadIdx.x;
    float partial = 0.0f;
    for (int d = tid; d < Dd; d += 256)
        partial = fmaf(hp[b * Dd + d], Wc[d * 2 + c], partial);
    __shared__ float red[256];
    red[tid] = partial;
    __syncthreads();
    for (int s = 128; s > 0; s >>= 1) {
        if (tid < s) red[tid] += red[tid + s];
        __syncthreads();
    }
    if (tid == 0) out[b * 2 + c] = red[0] + bc[c];
}

extern "C" void kernel_launch(void* const* d_in, const int* in_sizes, int n_in,
                              void* d_out, int out_size, void* d_ws, size_t ws_size,
                              hipStream_t stream)
{
    const float* x    = (const float*)d_in[0];
    const float* x_r  = (const float*)d_in[1];
    const float* x_w  = (const float*)d_in[2];
    const float* x_k  = (const float*)d_in[3];
    const float* x_v  = (const float*)d_in[4];
    const float* x_a  = (const float*)d_in[5];
    const float* x_g  = (const float*)d_in[6];
    const float* W_r  = (const float*)d_in[7];
    const float* W_k  = (const float*)d_in[8];
    const float* W_v  = (const float*)d_in[9];
    const float* W_o  = (const float*)d_in[10];
    const float* w0   = (const float*)d_in[11];
    const float* w1   = (const float*)d_in[12];
    const float* w2   = (const float*)d_in[13];
    const float* a0   = (const float*)d_in[14];
    const float* a1   = (const float*)d_in[15];
    const float* a2   = (const float*)d_in[16];
    const float* g1   = (const float*)d_in[17];
    const float* g2   = (const float*)d_in[18];
    const float* k_k  = (const float*)d_in[19];
    const float* k_a  = (const float*)d_in[20];
    const float* r_k  = (const float*)d_in[21];
    const float* gn_w = (const float*)d_in[22];
    const float* gn_b = (const float*)d_in[23];
    const float* Wcls = (const float*)d_in[24];
    const float* bcls = (const float*)d_in[25];
    float* out = (float*)d_out;

    const size_t MD = (size_t)Mm * Dd;
    char* w = (char*)d_ws;
    u16* S0 = (u16*)w; w += MD * 2;   // xr -> decay -> g
    u16* S1 = (u16*)w; w += MD * 2;   // xk -> a/b
    u16* S2 = (u16*)w; w += MD * 2;   // xv -> kk -> o2
    u16* S3 = (u16*)w; w += MD * 2;   // xw -> r
    u16* S4 = (u16*)w; w += MD * 2;   // xa -> k
    u16* S5 = (u16*)w; w += MD * 2;   // xg -> v
    u16* S6 = (u16*)w; w += MD * 2;   // scan out o
    u16* TW = (u16*)w; w += (size_t)Mm * 64 * 2;
    u16* TA = (u16*)w; w += (size_t)Mm * 64 * 2;
    u16* TG = (u16*)w; w += (size_t)Mm * 160 * 2;
    float* bufH = (float*)w; w += (size_t)Bb * Dd * 4;

    dim3 blk(256);
    dim3 gMix(Mm);
    dim3 gMf(Mm / 128, 1024 / 128);
    dim3 g64(Mm / TILE_M, 1);
    dim3 g160(Mm / TILE_M, 3);

    mix6_kernel<<<gMix, blk, 0, stream>>>(x, x_r, x_k, x_v, x_w, x_a, x_g,
                                          S0, S1, S2, S3, S4, S5);
    sgemm_small<<<g64,  blk, 0, stream>>>(S3, Dd, w1, 64,  TW, 64,  64,  Dd, 1);
    sgemm_small<<<g64,  blk, 0, stream>>>(S4, Dd, a1, 64,  TA, 64,  64,  Dd, 0);
    sgemm_small<<<g160, blk, 0, stream>>>(S5, Dd, g1, 160, TG, 160, 160, Dd, 2);
    gemm_mfma<0, false><<<gMf, blk, 0, stream>>>(S0, Dd, W_r, nullptr, S3, Dd);
    gemm_mfma<0, false><<<gMf, blk, 0, stream>>>(S1, Dd, W_k, nullptr, S4, Dd);
    gemm_mfma<0, false><<<gMf, blk, 0, stream>>>(S2, Dd, W_v, nullptr, S5, Dd);
    gemm_mfma<3, true><<<gMf, blk, 0, stream>>>(TW, 64, w2, w0, S0, 64);
    gemm_mfma<2, true><<<gMf, blk, 0, stream>>>(TA, 64, a2, a0, S1, 64);
    ew_kv_kernel<<<Mm, blk, 0, stream>>>(S4, S1, S2, k_k, k_a);
    scan_kernel<<<Bb * Hh, blk, 0, stream>>>(S3, S0, S4, S5, S2, S1, S6);
    gemm_mfma<0, false><<<gMf, blk, 0, stream>>>(TG, 160, g2, nullptr, S0, 160);
    gn_kernel<<<Mm, blk, 0, stream>>>(S6, S3, S4, S5, S0, gn_w, gn_b, r_k, S2);
    zero_kernel<<<(Bb * Dd + 255) / 256, blk, 0, stream>>>(bufH, Bb * Dd);
    gemm_wo_mfma<<<gMf, blk, 0, stream>>>(S2, W_o, bufH);
    cls_kernel<<<32, blk, 0, stream>>>(bufH, Wcls, bcls, out);
}

// Round 12
// 1589.986 us; speedup vs baseline: 1.2954x; 1.2954x over previous
//
#include <hip/hip_runtime.h>
#include <hip/hip_bf16.h>

typedef unsigned short u16;
typedef unsigned int u32;

#define Bb 16
#define Tt 1024
#define Dd 1024
#define Nn 64
#define Hh 16
#define Mm (Bb*Tt)

#define TILE_M 64
#define TILE_N 64
#define TILE_K 16

typedef float f32x4 __attribute__((ext_vector_type(4)));
typedef short s16x8 __attribute__((ext_vector_type(8)));

struct __align__(8) u16x4s { u16 x, y, z, w; };

__device__ __forceinline__ float bf2f(u16 u) { return __uint_as_float(((u32)u) << 16); }
__device__ __forceinline__ u16 f2bf(float f) {
    __hip_bfloat16 h = __float2bfloat16(f);
    return *reinterpret_cast<u16*>(&h);
}
__device__ __forceinline__ float sigf(float x) { return 1.0f / (1.0f + expf(-x)); }

// ---------------- transpose+convert: in[K][N] f32 -> out[N][K] bf16 ----------------
__global__ __launch_bounds__(256)
void transpose_w(const float* __restrict__ in, u16* __restrict__ out, int K, int N)
{
    __shared__ u16 tile[32][33];
    const int k0 = blockIdx.x * 32, n0 = blockIdx.y * 32;
    const int tx = threadIdx.x & 31, ty = threadIdx.x >> 5;   // 32 x 8
#pragma unroll
    for (int i = 0; i < 32; i += 8)
        tile[ty + i][tx] = f2bf(in[(size_t)(k0 + ty + i) * N + n0 + tx]);
    __syncthreads();
#pragma unroll
    for (int i = 0; i < 32; i += 8)
        out[(size_t)(n0 + ty + i) * K + k0 + tx] = tile[tx][ty + i];
}

// ---------------- mix6 ----------------
__global__ __launch_bounds__(256)
void mix6_kernel(const float* __restrict__ x,
                 const float* __restrict__ cr, const float* __restrict__ ck,
                 const float* __restrict__ cv, const float* __restrict__ cw,
                 const float* __restrict__ ca, const float* __restrict__ cg,
                 u16* __restrict__ o0, u16* __restrict__ o1, u16* __restrict__ o2,
                 u16* __restrict__ o3, u16* __restrict__ o4, u16* __restrict__ o5)
{
    const int m = blockIdx.x;
    const int c0 = threadIdx.x * 4;
    const size_t base = (size_t)m * Dd + c0;
    float4 xc = *(const float4*)(x + base);
    float4 xp = make_float4(0.f, 0.f, 0.f, 0.f);
    if (m & (Tt - 1)) xp = *(const float4*)(x + base - Dd);
    float dx[4] = {xp.x - xc.x, xp.y - xc.y, xp.z - xc.z, xp.w - xc.w};
    float xv[4] = {xc.x, xc.y, xc.z, xc.w};
    const float* cfs[6] = {cr, ck, cv, cw, ca, cg};
    u16* outs[6] = {o0, o1, o2, o3, o4, o5};
#pragma unroll
    for (int s = 0; s < 6; ++s) {
        float4 cf = *(const float4*)(cfs[s] + c0);
        float c4[4] = {cf.x, cf.y, cf.z, cf.w};
        u16x4s ov;
        u16* op = &ov.x;
#pragma unroll
        for (int l = 0; l < 4; ++l) op[l] = f2bf(fmaf(dx[l], c4[l], xv[l]));
        *(u16x4s*)(outs[s] + base) = ov;
    }
}

// ---------------- small fp32-compute GEMM for LoRA stage-1 ----------------
__global__ __launch_bounds__(256)
void sgemm_small(const u16* __restrict__ A, int lda,
                 const float* __restrict__ Bw, int ldb,
                 u16* __restrict__ C, int ldc,
                 int N, int K, int act)
{
    __shared__ float As[TILE_K][TILE_M + 1];
    __shared__ float Bs[TILE_K][TILE_N + 1];
    const int tid = threadIdx.x;
    const int tx = tid & 15, ty = tid >> 4;
    const int bm = blockIdx.x * TILE_M;
    const int bn = blockIdx.y * TILE_N;

    float acc[4][4] = {};

    for (int k0 = 0; k0 < K; k0 += TILE_K) {
#pragma unroll
        for (int l = 0; l < 4; ++l) {
            int idx = l * 256 + tid;
            int kk = idx & 15, mm = idx >> 4;
            As[kk][mm] = bf2f(A[(size_t)(bm + mm) * lda + k0 + kk]);
        }
#pragma unroll
        for (int l = 0; l < 4; ++l) {
            int idx = l * 256 + tid;
            int nn = idx & 63, kk = idx >> 6;
            int gn = bn + nn;
            Bs[kk][nn] = (gn < N) ? Bw[(size_t)(k0 + kk) * ldb + gn] : 0.0f;
        }
        __syncthreads();
#pragma unroll
        for (int kk = 0; kk < TILE_K; ++kk) {
            float af[4], bf[4];
#pragma unroll
            for (int i = 0; i < 4; ++i) af[i] = As[kk][ty * 4 + i];
#pragma unroll
            for (int j = 0; j < 4; ++j) bf[j] = Bs[kk][tx * 4 + j];
#pragma unroll
            for (int i = 0; i < 4; ++i)
#pragma unroll
                for (int j = 0; j < 4; ++j)
                    acc[i][j] = fmaf(af[i], bf[j], acc[i][j]);
        }
        __syncthreads();
    }

#pragma unroll
    for (int i = 0; i < 4; ++i) {
        int gm = bm + ty * 4 + i;
#pragma unroll
        for (int j = 0; j < 4; ++j) {
            int gn = bn + tx * 4 + j;
            if (gn >= N) continue;
            float v = acc[i][j];
            if (act == 1) v = tanhf(v);
            else if (act == 2) v = sigf(v);
            C[(size_t)gm * ldc + gn] = f2bf(v);
        }
    }
}

// ---------------- MFMA GEMM: both operands bf16, B pre-transposed [N][K] ----------------
template<int ACT, bool HAS_BIAS>
__global__ __launch_bounds__(256)
void gemm_mfma(const u16* __restrict__ A, int lda,
               const u16* __restrict__ Bt,
               const float* __restrict__ bias,
               u16* __restrict__ C, int K)
{
    __shared__ u16 As[128][40];
    __shared__ u16 Bs[128][40];
    const int tid = threadIdx.x;
    const int bm = blockIdx.x * 128, bn = blockIdx.y * 128;
    const int lane = tid & 63, w = tid >> 6;
    const int wr = w >> 1, wc = w & 1;
    const int lr = lane & 15, kg = lane >> 4;

    f32x4 acc[4][4];
#pragma unroll
    for (int m = 0; m < 4; ++m)
#pragma unroll
        for (int n = 0; n < 4; ++n) acc[m][n] = (f32x4){0.f, 0.f, 0.f, 0.f};

    const int row = tid >> 2, part = tid & 3;
    for (int k0 = 0; k0 < K; k0 += 32) {
        *(s16x8*)&As[row][part * 8] =
            *(const s16x8*)(A + (size_t)(bm + row) * lda + k0 + part * 8);
        *(s16x8*)&As[row + 64][part * 8] =
            *(const s16x8*)(A + (size_t)(bm + row + 64) * lda + k0 + part * 8);
        *(s16x8*)&Bs[row][part * 8] =
            *(const s16x8*)(Bt + (size_t)(bn + row) * K + k0 + part * 8);
        *(s16x8*)&Bs[row + 64][part * 8] =
            *(const s16x8*)(Bt + (size_t)(bn + row + 64) * K + k0 + part * 8);
        __syncthreads();
        s16x8 af[4], bfr[4];
#pragma unroll
        for (int m = 0; m < 4; ++m)
            af[m] = *(const s16x8*)&As[wr * 64 + m * 16 + lr][kg * 8];
#pragma unroll
        for (int n = 0; n < 4; ++n)
            bfr[n] = *(const s16x8*)&Bs[wc * 64 + n * 16 + lr][kg * 8];
#pragma unroll
        for (int m = 0; m < 4; ++m)
#pragma unroll
            for (int n = 0; n < 4; ++n)
                acc[m][n] = __builtin_amdgcn_mfma_f32_16x16x32_bf16(af[m], bfr[n], acc[m][n], 0, 0, 0);
        __syncthreads();
    }

#pragma unroll
    for (int n = 0; n < 4; ++n) {
        int col = bn + wc * 64 + n * 16 + lr;
        float bv = HAS_BIAS ? bias[col] : 0.0f;
#pragma unroll
        for (int m = 0; m < 4; ++m) {
            int row0 = bm + wr * 64 + m * 16 + kg * 4;
#pragma unroll
            for (int r = 0; r < 4; ++r) {
                float v = acc[m][n][r] + bv;
                if (ACT == 2) v = sigf(v);
                else if (ACT == 3) {
                    float ww = -log1pf(expf(-v)) - 0.5f;
                    v = expf(-expf(ww));
                }
                C[(size_t)(row0 + r) * 1024 + col] = f2bf(v);
            }
        }
    }
}

// ---------------- W_o MFMA GEMM (bf16 W^T) with fused relu-colmax -> atomicMax ----------------
__global__ __launch_bounds__(256)
void gemm_wo_mfma(const u16* __restrict__ A,
                  const u16* __restrict__ Bt,
                  float* __restrict__ Hbuf)
{
    __shared__ u16 As[128][40];
    __shared__ u16 Bs[128][40];
    const int tid = threadIdx.x;
    const int bm = blockIdx.x * 128, bn = blockIdx.y * 128;
    const int lane = tid & 63, w = tid >> 6;
    const int wr = w >> 1, wc = w & 1;
    const int lr = lane & 15, kg = lane >> 4;

    f32x4 acc[4][4];
#pragma unroll
    for (int m = 0; m < 4; ++m)
#pragma unroll
        for (int n = 0; n < 4; ++n) acc[m][n] = (f32x4){0.f, 0.f, 0.f, 0.f};

    const int row = tid >> 2, part = tid & 3;
    for (int k0 = 0; k0 < 1024; k0 += 32) {
        *(s16x8*)&As[row][part * 8] =
            *(const s16x8*)(A + (size_t)(bm + row) * 1024 + k0 + part * 8);
        *(s16x8*)&As[row + 64][part * 8] =
            *(const s16x8*)(A + (size_t)(bm + row + 64) * 1024 + k0 + part * 8);
        *(s16x8*)&Bs[row][part * 8] =
            *(const s16x8*)(Bt + (size_t)(bn + row) * 1024 + k0 + part * 8);
        *(s16x8*)&Bs[row + 64][part * 8] =
            *(const s16x8*)(Bt + (size_t)(bn + row + 64) * 1024 + k0 + part * 8);
        __syncthreads();
        s16x8 af[4], bfr[4];
#pragma unroll
        for (int m = 0; m < 4; ++m)
            af[m] = *(const s16x8*)&As[wr * 64 + m * 16 + lr][kg * 8];
#pragma unroll
        for (int n = 0; n < 4; ++n)
            bfr[n] = *(const s16x8*)&Bs[wc * 64 + n * 16 + lr][kg * 8];
#pragma unroll
        for (int m = 0; m < 4; ++m)
#pragma unroll
            for (int n = 0; n < 4; ++n)
                acc[m][n] = __builtin_amdgcn_mfma_f32_16x16x32_bf16(af[m], bfr[n], acc[m][n], 0, 0, 0);
        __syncthreads();
    }

    const int b = bm >> 10;
#pragma unroll
    for (int n = 0; n < 4; ++n) {
        float mv = -1e30f;
#pragma unroll
        for (int m = 0; m < 4; ++m)
#pragma unroll
            for (int r = 0; r < 4; ++r) mv = fmaxf(mv, acc[m][n][r]);
        mv = fmaxf(mv, __shfl_xor(mv, 16));
        mv = fmaxf(mv, __shfl_xor(mv, 32));
        mv = fmaxf(mv, 0.0f);
        if (lane < 16) {
            int col = bn + wc * 64 + n * 16 + lr;
            atomicMax((u32*)&Hbuf[b * Dd + col], __float_as_uint(mv));
        }
    }
}

// ---------------- kk / k-mod / b ----------------
__global__ __launch_bounds__(256)
void ew_kv_kernel(u16* __restrict__ kbuf, u16* __restrict__ abuf,
                  u16* __restrict__ kkbuf,
                  const float* __restrict__ k_k, const float* __restrict__ k_a)
{
    const int m = blockIdx.x;
    const int tid = threadIdx.x;
    const int c0 = tid * 4;
    const size_t base = (size_t)m * Dd + c0;
    u16x4s kv4 = *(const u16x4s*)(kbuf + base);
    u16x4s av4 = *(const u16x4s*)(abuf + base);
    float4 kkc = *(const float4*)(k_k + c0);
    float4 kac = *(const float4*)(k_a + c0);

    float kin[4] = {bf2f(kv4.x), bf2f(kv4.y), bf2f(kv4.z), bf2f(kv4.w)};
    float ain[4] = {bf2f(av4.x), bf2f(av4.y), bf2f(av4.z), bf2f(av4.w)};
    float kkc4[4] = {kkc.x, kkc.y, kkc.z, kkc.w};
    float kac4[4] = {kac.x, kac.y, kac.z, kac.w};

    float kr[4];
#pragma unroll
    for (int l = 0; l < 4; ++l) kr[l] = kin[l] * kkc4[l];
    float ss = kr[0]*kr[0] + kr[1]*kr[1] + kr[2]*kr[2] + kr[3]*kr[3];
#pragma unroll
    for (int mask = 1; mask < 16; mask <<= 1) ss += __shfl_xor(ss, mask);
    float inv = 1.0f / fmaxf(sqrtf(ss), 1e-12f);

    u16x4s kkv, kmv, bvv;
    u16* kkp = &kkv.x; u16* kmp = &kmv.x; u16* bvp = &bvv.x;
#pragma unroll
    for (int l = 0; l < 4; ++l) {
        float kkf = kr[l] * inv;
        kkp[l] = f2bf(kkf);
        kmp[l] = f2bf(kin[l] * (1.0f + (ain[l] - 1.0f) * kac4[l]));
        bvp[l] = f2bf(kkf * ain[l]);
    }
    *(u16x4s*)(kkbuf + base) = kkv;
    *(u16x4s*)(kbuf  + base) = kmv;
    *(u16x4s*)(abuf  + base) = bvv;
}

// ---------------- RWKV7 scan: r9 version (barrier-free per-wave LDS staging) ----------------
__global__ __launch_bounds__(256)
void scan_kernel(const u16* __restrict__ rb, const u16* __restrict__ db,
                 const u16* __restrict__ kb, const u16* __restrict__ vb,
                 const u16* __restrict__ kkb, const u16* __restrict__ bvb,
                 u16* __restrict__ ob)
{
    const int blk = blockIdx.x;
    const int batch = blk >> 4, head = blk & 15;
    const int tid = threadIdx.x;
    const int w = tid >> 6;
    const int lane = tid & 63;
    const int q = lane & 3, il = lane >> 2;
    const int i = w * 16 + il;
    const int j0 = q * 16;

    __shared__ float ws[4][2][6][64];

    const size_t rowbase = (size_t)batch * Tt * Dd + head * Nn;

    float S[16];
#pragma unroll
    for (int jj = 0; jj < 16; ++jj) S[jj] = 0.0f;

    {
        size_t off = rowbase + lane;
        ws[w][0][0][lane] = bf2f(rb[off]);
        ws[w][0][1][lane] = bf2f(db[off]);
        ws[w][0][2][lane] = bf2f(kb[off]);
        ws[w][0][3][lane] = bf2f(vb[off]);
        ws[w][0][4][lane] = bf2f(kkb[off]);
        ws[w][0][5][lane] = bf2f(bvb[off]);
    }
    u16 p0 = 0, p1 = 0, p2 = 0, p3 = 0, p4 = 0, p5 = 0;
    {
        size_t off = rowbase + Dd + lane;
        p0 = rb[off]; p1 = db[off]; p2 = kb[off];
        p3 = vb[off]; p4 = kkb[off]; p5 = bvb[off];
    }

    int c = 0;
    for (int t = 0; t < Tt; ++t) {
        if (t + 1 < Tt) {
            ws[w][c ^ 1][0][lane] = bf2f(p0);
            ws[w][c ^ 1][1][lane] = bf2f(p1);
            ws[w][c ^ 1][2][lane] = bf2f(p2);
            ws[w][c ^ 1][3][lane] = bf2f(p3);
            ws[w][c ^ 1][4][lane] = bf2f(p4);
            ws[w][c ^ 1][5][lane] = bf2f(p5);
        }
        if (t + 2 < Tt) {
            size_t off = rowbase + (size_t)(t + 2) * Dd + lane;
            p0 = rb[off]; p1 = db[off]; p2 = kb[off];
            p3 = vb[off]; p4 = kkb[off]; p5 = bvb[off];
        }

        float rv[16], dec[16], kv[16], kkv[16], bv[16];
#pragma unroll
        for (int u = 0; u < 4; ++u) {
            *(float4*)&rv[u*4]  = *(const float4*)&ws[w][c][0][j0 + u*4];
            *(float4*)&dec[u*4] = *(const float4*)&ws[w][c][1][j0 + u*4];
            *(float4*)&kv[u*4]  = *(const float4*)&ws[w][c][2][j0 + u*4];
            *(float4*)&kkv[u*4] = *(const float4*)&ws[w][c][4][j0 + u*4];
            *(float4*)&bv[u*4]  = *(const float4*)&ws[w][c][5][j0 + u*4];
        }
        float vi = ws[w][c][3][i];

        float sa = 0.0f;
#pragma unroll
        for (int jj = 0; jj < 16; ++jj) sa = fmaf(S[jj], kkv[jj], sa);
        sa = -sa;
        sa += __shfl_xor(sa, 1);
        sa += __shfl_xor(sa, 2);

        float op = 0.0f;
#pragma unroll
        for (int jj = 0; jj < 16; ++jj) {
            float Sv = S[jj] * dec[jj];
            Sv = fmaf(sa, bv[jj], Sv);
            Sv = fmaf(vi, kv[jj], Sv);
            S[jj] = Sv;
            op = fmaf(Sv, rv[jj], op);
        }
        op += __shfl_xor(op, 1);
        op += __shfl_xor(op, 2);
        if (q == 0) ob[rowbase + (size_t)t * Dd + i] = f2bf(op);

        c ^= 1;
    }
}

// ---------------- GroupNorm + bonus + gate ----------------
__global__ __launch_bounds__(256)
void gn_kernel(const u16* __restrict__ ob, const u16* __restrict__ rb,
               const u16* __restrict__ kb, const u16* __restrict__ vb,
               const u16* __restrict__ gb,
               const float* __restrict__ gn_w, const float* __restrict__ gn_b,
               const float* __restrict__ r_k, u16* __restrict__ o2)
{
    const int m = blockIdx.x;
    const int tid = threadIdx.x;
    const int c0 = tid * 4;
    const int h = tid >> 4;
    const int jh = c0 & 63;
    const size_t base = (size_t)m * Dd + c0;

    u16x4s ov4 = *(const u16x4s*)(ob + base);
    u16x4s rv4 = *(const u16x4s*)(rb + base);
    u16x4s kv4 = *(const u16x4s*)(kb + base);
    u16x4s vv4 = *(const u16x4s*)(vb + base);
    u16x4s gv4 = *(const u16x4s*)(gb + base);
    float4 rkc = *(const float4*)(r_k + h * 64 + jh);

    float ovv[4] = {bf2f(ov4.x), bf2f(ov4.y), bf2f(ov4.z), bf2f(ov4.w)};
    float rv[4] = {bf2f(rv4.x), bf2f(rv4.y), bf2f(rv4.z), bf2f(rv4.w)};
    float kv[4] = {bf2f(kv4.x), bf2f(kv4.y), bf2f(kv4.z), bf2f(kv4.w)};
    float vv[4] = {bf2f(vv4.x), bf2f(vv4.y), bf2f(vv4.z), bf2f(vv4.w)};
    float gv[4] = {bf2f(gv4.x), bf2f(gv4.y), bf2f(gv4.z), bf2f(gv4.w)};
    float rk4[4] = {rkc.x, rkc.y, rkc.z, rkc.w};

    float s1 = ovv[0] + ovv[1] + ovv[2] + ovv[3];
    float s2 = ovv[0]*ovv[0] + ovv[1]*ovv[1] + ovv[2]*ovv[2] + ovv[3]*ovv[3];
    float sb = rv[0]*kv[0]*rk4[0] + rv[1]*kv[1]*rk4[1] + rv[2]*kv[2]*rk4[2] + rv[3]*kv[3]*rk4[3];
#pragma unroll
    for (int mask = 1; mask < 16; mask <<= 1) {
        s1 += __shfl_xor(s1, mask);
        s2 += __shfl_xor(s2, mask);
        sb += __shfl_xor(sb, mask);
    }
    float mu = s1 * (1.0f / 64.0f);
    float var = s2 * (1.0f / 64.0f) - mu * mu;
    float rstd = rsqrtf(var + 6.4e-4f);

    float4 gwv = *(const float4*)(gn_w + c0);
    float4 gbv = *(const float4*)(gn_b + c0);
    float gw4[4] = {gwv.x, gwv.y, gwv.z, gwv.w};
    float gb4[4] = {gbv.x, gbv.y, gbv.z, gbv.w};

    u16x4s outv; u16* op = &outv.x;
#pragma unroll
    for (int l = 0; l < 4; ++l) {
        float v = (((ovv[l] - mu) * rstd) * gw4[l] + gb4[l] + sb * vv[l]) * gv[l];
        op[l] = f2bf(v);
    }
    *(u16x4s*)(o2 + base) = outv;
}

__global__ __launch_bounds__(256)
void zero_kernel(float* __restrict__ p, int n)
{
    int i = blockIdx.x * 256 + threadIdx.x;
    if (i < n) p[i] = 0.0f;
}

__global__ __launch_bounds__(256)
void cls_kernel(const float* __restrict__ hp, const float* __restrict__ Wc,
                const float* __restrict__ bc, float* __restrict__ out)
{
    const int p = blockIdx.x;
    const int b = p >> 1, c = p & 1;
    const int tid = threadIdx.x;
    float partial = 0.0f;
    for (int d = tid; d < Dd; d += 256)
        partial = fmaf(hp[b * Dd + d], Wc[d * 2 + c], partial);
    __shared__ float red[256];
    red[tid] = partial;
    __syncthreads();
    for (int s = 128; s > 0; s >>= 1) {
        if (tid < s) red[tid] += red[tid + s];
        __syncthreads();
    }
    if (tid == 0) out[b * 2 + c] = red[0] + bc[c];
}

extern "C" void kernel_launch(void* const* d_in, const int* in_sizes, int n_in,
                              void* d_out, int out_size, void* d_ws, size_t ws_size,
                              hipStream_t stream)
{
    const float* x    = (const float*)d_in[0];
    const float* x_r  = (const float*)d_in[1];
    const float* x_w  = (const float*)d_in[2];
    const float* x_k  = (const float*)d_in[3];
    const float* x_v  = (const float*)d_in[4];
    const float* x_a  = (const float*)d_in[5];
    const float* x_g  = (const float*)d_in[6];
    const float* W_r  = (const float*)d_in[7];
    const float* W_k  = (const float*)d_in[8];
    const float* W_v  = (const float*)d_in[9];
    const float* W_o  = (const float*)d_in[10];
    const float* w0   = (const float*)d_in[11];
    const float* w1   = (const float*)d_in[12];
    const float* w2   = (const float*)d_in[13];
    const float* a0   = (const float*)d_in[14];
    const float* a1   = (const float*)d_in[15];
    const float* a2   = (const float*)d_in[16];
    const float* g1   = (const float*)d_in[17];
    const float* g2   = (const float*)d_in[18];
    const float* k_k  = (const float*)d_in[19];
    const float* k_a  = (const float*)d_in[20];
    const float* r_k  = (const float*)d_in[21];
    const float* gn_w = (const float*)d_in[22];
    const float* gn_b = (const float*)d_in[23];
    const float* Wcls = (const float*)d_in[24];
    const float* bcls = (const float*)d_in[25];
    float* out = (float*)d_out;

    const size_t MD = (size_t)Mm * Dd;
    char* w = (char*)d_ws;
    u16* S0 = (u16*)w; w += MD * 2;   // xr -> decay -> g
    u16* S1 = (u16*)w; w += MD * 2;   // xk -> a/b
    u16* S2 = (u16*)w; w += MD * 2;   // xv -> kk -> o2
    u16* S3 = (u16*)w; w += MD * 2;   // xw -> r
    u16* S4 = (u16*)w; w += MD * 2;   // xa -> k
    u16* S5 = (u16*)w; w += MD * 2;   // xg -> v
    u16* S6 = (u16*)w; w += MD * 2;   // scan out o
    u16* TW = (u16*)w; w += (size_t)Mm * 64 * 2;
    u16* TA = (u16*)w; w += (size_t)Mm * 64 * 2;
    u16* TG = (u16*)w; w += (size_t)Mm * 160 * 2;
    float* bufH = (float*)w; w += (size_t)Bb * Dd * 4;
    u16* WtR = (u16*)w; w += (size_t)1024 * 1024 * 2;   // 2MB each
    u16* WtK = (u16*)w; w += (size_t)1024 * 1024 * 2;
    u16* WtV = (u16*)w; w += (size_t)1024 * 1024 * 2;
    u16* WtO = (u16*)w; w += (size_t)1024 * 1024 * 2;
    u16* W2t = (u16*)w; w += (size_t)1024 * 64 * 2;
    u16* A2t = (u16*)w; w += (size_t)1024 * 64 * 2;
    u16* G2t = (u16*)w; w += (size_t)1024 * 160 * 2;

    dim3 blk(256);
    dim3 gMix(Mm);
    dim3 gMf(Mm / 128, 1024 / 128);
    dim3 g64(Mm / TILE_M, 1);
    dim3 g160(Mm / TILE_M, 3);
    dim3 gT(32, 32);       // K=1024 transposes
    dim3 gT64(2, 32);      // K=64
    dim3 gT160(5, 32);     // K=160

    mix6_kernel<<<gMix, blk, 0, stream>>>(x, x_r, x_k, x_v, x_w, x_a, x_g,
                                          S0, S1, S2, S3, S4, S5);
    // pre-transpose+convert weights to bf16 [N][K]
    transpose_w<<<gT,    blk, 0, stream>>>(W_r, WtR, 1024, 1024);
    transpose_w<<<gT,    blk, 0, stream>>>(W_k, WtK, 1024, 1024);
    transpose_w<<<gT,    blk, 0, stream>>>(W_v, WtV, 1024, 1024);
    transpose_w<<<gT,    blk, 0, stream>>>(W_o, WtO, 1024, 1024);
    transpose_w<<<gT64,  blk, 0, stream>>>(w2,  W2t, 64,   1024);
    transpose_w<<<gT64,  blk, 0, stream>>>(a2,  A2t, 64,   1024);
    transpose_w<<<gT160, blk, 0, stream>>>(g2,  G2t, 160,  1024);

    sgemm_small<<<g64,  blk, 0, stream>>>(S3, Dd, w1, 64,  TW, 64,  64,  Dd, 1);
    sgemm_small<<<g64,  blk, 0, stream>>>(S4, Dd, a1, 64,  TA, 64,  64,  Dd, 0);
    sgemm_small<<<g160, blk, 0, stream>>>(S5, Dd, g1, 160, TG, 160, 160, Dd, 2);
    gemm_mfma<0, false><<<gMf, blk, 0, stream>>>(S0, Dd, WtR, nullptr, S3, 1024);
    gemm_mfma<0, false><<<gMf, blk, 0, stream>>>(S1, Dd, WtK, nullptr, S4, 1024);
    gemm_mfma<0, false><<<gMf, blk, 0, stream>>>(S2, Dd, WtV, nullptr, S5, 1024);
    gemm_mfma<3, true><<<gMf, blk, 0, stream>>>(TW, 64, W2t, w0, S0, 64);
    gemm_mfma<2, true><<<gMf, blk, 0, stream>>>(TA, 64, A2t, a0, S1, 64);
    ew_kv_kernel<<<Mm, blk, 0, stream>>>(S4, S1, S2, k_k, k_a);
    scan_kernel<<<Bb * Hh, blk, 0, stream>>>(S3, S0, S4, S5, S2, S1, S6);
    gemm_mfma<0, false><<<gMf, blk, 0, stream>>>(TG, 160, G2t, nullptr, S0, 160);
    gn_kernel<<<Mm, blk, 0, stream>>>(S6, S3, S4, S5, S0, gn_w, gn_b, r_k, S2);
    zero_kernel<<<(Bb * Dd + 255) / 256, blk, 0, stream>>>(bufH, Bb * Dd);
    gemm_wo_mfma<<<gMf, blk, 0, stream>>>(S2, WtO, bufH);
    cls_kernel<<<32, blk, 0, stream>>>(bufH, Wcls, bcls, out);
}